// Round 19
// baseline (526.026 us; speedup 1.0000x reference)
//
#include <hip/hip_runtime.h>
#include <hip/hip_bf16.h>
#include <math.h>

// VQ quantizer: SINGLE-PASS bf16-MFMA prefilter (128x256 tile) + fp32-chain-exact
// rescore.  Exact semantics (validated r2/r4/r6): dist = fl32(fl32(r2+e2) -
// 2*fma_chain(x.e)), argmin first-min-wins.
// Capture (r18-validated stats): per-block LDS blockmin over the FULL 256-col
//   strip; thr = min(plain rowMinU, blockmin) + M >= gmin + M >= gmin + 2delta
//   -> winner always captured in its own strip; staleness only loosens.
//   Worst-case captures 32 strips x e^{M/beta256} ~= 66 << CAP=128.
//   Exact full-scan fallback on overflow (correctness net).
// Round 19: r18's 256x256 tile spilled (acc[8][4]=128 VGPR alone; WRITE 21.5MB
//   scratch, 371us). Rectangular 128x256 keeps BN=256 capture stats at r7's
//   acc[4][4] register cost; launch_bounds(512,2) -> 256-VGPR budget, no spill.
// Outputs (float32 flat): [loss | quantized(8192*256) | indices(8192 as float)]

#define NROWS 8192
#define DDIM  256
#define KCW   8192
#define CAP   128
#define MARGIN 5e-4f

typedef __attribute__((ext_vector_type(8))) short short8;
typedef __attribute__((ext_vector_type(4))) float f32x4;
typedef unsigned int u32;

__device__ inline void async_copy16(void* lds_uniform, const void* gsrc) {
  __builtin_amdgcn_global_load_lds(
      (const __attribute__((address_space(1))) u32*)gsrc,
      (__attribute__((address_space(3))) u32*)lds_uniform, 16, 0, 0);
}

__device__ inline unsigned fmap(float f) {
  unsigned b = __float_as_uint(f);
  return (b & 0x80000000u) ? ~b : (b | 0x80000000u);
}
__device__ inline float funmap(unsigned u) {
  unsigned b = (u & 0x80000000u) ? (u & 0x7FFFFFFFu) : ~u;
  return __uint_as_float(b);
}

// Fused: bf16 cast + e2 (f64->f32, cb rows) + rowMinU/cnt init (z rows).
// rowMinU init = fmap(+inf) = 0xFF800000 (funmap -> +inf, no NaN corners).
__global__ __launch_bounds__(256) void k_prep_cast(const float* __restrict__ z,
                                                   const float* __restrict__ cb,
                                                   ushort* __restrict__ zb,
                                                   ushort* __restrict__ cbb,
                                                   float* __restrict__ e2f,
                                                   unsigned* __restrict__ rowMinU,
                                                   unsigned* __restrict__ cnt) {
  int t = threadIdx.x, w = t >> 6, lane = t & 63;
  int wid = blockIdx.x * 4 + w;           // 0..16383
  bool isCb = wid >= NROWS;
  int row = isCb ? wid - NROWS : wid;
  const float* src = (isCb ? cb : z) + (size_t)row * DDIM + lane * 4;
  float4 v = *reinterpret_cast<const float4*>(src);
  ushort4 o;
  __hip_bfloat16 bx = __float2bfloat16(v.x); o.x = *(ushort*)&bx;
  __hip_bfloat16 by = __float2bfloat16(v.y); o.y = *(ushort*)&by;
  __hip_bfloat16 bz = __float2bfloat16(v.z); o.z = *(ushort*)&bz;
  __hip_bfloat16 bw = __float2bfloat16(v.w); o.w = *(ushort*)&bw;
  ushort* dst = (isCb ? cbb : zb) + (size_t)row * DDIM + lane * 4;
  *reinterpret_cast<ushort4*>(dst) = o;
  if (isCb) {
    double d = (double)v.x * v.x + (double)v.y * v.y + (double)v.z * v.z + (double)v.w * v.w;
#pragma unroll
    for (int off = 1; off < 64; off <<= 1) d += __shfl_xor(d, off);
    if (lane == 0) e2f[row] = (float)d;
  } else {
    if (lane == 0) { rowMinU[row] = 0xFF800000u; cnt[row] = 0; }
  }
}

// 128x256 tile MFMA GEMM, BK=64, 8 waves (2 row-groups x 4 col-groups), each wave
// 64x64 output (acc[4][4] = r7's proven register budget). global_load_lds staging,
// slot-XOR pre-swizzled source + XOR ds_read (r7-proven 0-conflict).
// Epilogue: pass A block-level LDS row-min (256 cols) -> barrier -> pass B capture.
__global__ __launch_bounds__(512, 2) void k_score1(const ushort* __restrict__ zb,
                                                   const ushort* __restrict__ cbb,
                                                   const float* __restrict__ e2f,
                                                   unsigned* __restrict__ rowMinU,
                                                   unsigned* __restrict__ cnt,
                                                   ushort* __restrict__ cand) {
  __shared__ ushort Ab[128 * 64];        // 16 KB
  __shared__ ushort Bb[256 * 64];        // 32 KB
  __shared__ unsigned blockmin[128];
  int t = threadIdx.x, w = t >> 6, lane = t & 63;
  int wg = ((blockIdx.x & 7) << 8) | (blockIdx.x >> 3);   // XCD swizzle (2048%8==0)
  int mt = wg >> 5, nt = wg & 31;        // mt 0..63, nt 0..31
  int wm = w >> 2, wn = w & 3;           // 2 x 4 wave grid
  int cl = lane & 15, g = lane >> 4;

  if (t < 128) blockmin[t] = 0xFF800000u;   // fmap(+inf); synced by ks-loop barriers

  int rloc8 = lane >> 3;                 // 0..7
  int sslot = (lane & 7) ^ rloc8;        // pre-swizzled source slot
  const ushort* arow_base = zb  + (size_t)(mt * 128) * DDIM;
  const ushort* brow_base = cbb + (size_t)(nt * 256) * DDIM;

  f32x4 acc[4][4];
#pragma unroll
  for (int m = 0; m < 4; ++m)
#pragma unroll
    for (int n = 0; n < 4; ++n) acc[m][n] = (f32x4){0.f, 0.f, 0.f, 0.f};

  for (int ks = 0; ks < 4; ++ks) {
#pragma unroll
    for (int i = 0; i < 6; ++i) {
      int ch = w * 6 + i;                            // 0..47, uniform per wave
      bool isA = ch < 16;
      int ct = isA ? ch : ch - 16;                   // A: 0..15, B: 0..31
      int row = ct * 8 + rloc8;
      const ushort* src = isA
          ? arow_base + (size_t)row * DDIM + ks * 64 + sslot * 8
          : brow_base + (size_t)row * DDIM + ks * 64 + sslot * 8;
      char* ldsb = (char*)(isA ? Ab : Bb) + ct * 1024;   // uniform base
      async_copy16(ldsb, src);
    }
    __syncthreads();                                  // drains vmcnt (compiler)
#pragma unroll
    for (int kk = 0; kk < 2; ++kk) {
      short8 af[4], bf[4];
#pragma unroll
      for (int m = 0; m < 4; ++m) {
        int arow = wm * 64 + m * 16 + cl;
        int ab = arow * 128 + (((kk * 4 + g) ^ (arow & 7)) << 4);
        af[m] = *reinterpret_cast<const short8*>((char*)Ab + ab);
      }
#pragma unroll
      for (int n = 0; n < 4; ++n) {
        int brow = wn * 64 + n * 16 + cl;
        int bb = brow * 128 + (((kk * 4 + g) ^ (brow & 7)) << 4);
        bf[n] = *reinterpret_cast<const short8*>((char*)Bb + bb);
      }
#pragma unroll
      for (int m = 0; m < 4; ++m)
#pragma unroll
        for (int n = 0; n < 4; ++n)
          acc[m][n] = __builtin_amdgcn_mfma_f32_16x16x32_bf16(af[m], bf[n], acc[m][n], 0, 0, 0);
    }
    __syncthreads();
  }

  // epilogue: C/D layout col=lane&15, row=(lane>>4)*4+j  [m89/m91]
  int col_base = nt * 256 + wn * 64;
  int row_base = mt * 128 + wm * 64;
  float e2v[4];
#pragma unroll
  for (int n = 0; n < 4; ++n) e2v[n] = e2f[col_base + n * 16 + cl];

  // hoisted global-min estimates: 16 independent plain loads (ILP, no atomics)
  float gm[4][4];
#pragma unroll
  for (int m = 0; m < 4; ++m)
#pragma unroll
    for (int j = 0; j < 4; ++j)
      gm[m][j] = funmap(rowMinU[row_base + m * 16 + g * 4 + j]);

  // PASS A: wave 64-col mins -> LDS blockmin (full 256-col strip min per row)
#pragma unroll
  for (int m = 0; m < 4; ++m) {
#pragma unroll
    for (int j = 0; j < 4; ++j) {
      float s0 = __fsub_rn(e2v[0], __fmul_rn(2.0f, acc[m][0][j]));
      float s1 = __fsub_rn(e2v[1], __fmul_rn(2.0f, acc[m][1][j]));
      float s2 = __fsub_rn(e2v[2], __fmul_rn(2.0f, acc[m][2][j]));
      float s3 = __fsub_rn(e2v[3], __fmul_rn(2.0f, acc[m][3][j]));
      float mn = fminf(fminf(s0, s1), fminf(s2, s3));
#pragma unroll
      for (int off = 1; off < 16; off <<= 1)
        mn = fminf(mn, __shfl_xor(mn, off));
      if (cl == 0) atomicMin(&blockmin[wm * 64 + m * 16 + g * 4 + j], fmap(mn));
    }
  }
  __syncthreads();

  // PASS B: capture vs min(global estimate, block 256-col min) + M
#pragma unroll
  for (int m = 0; m < 4; ++m) {
#pragma unroll
    for (int j = 0; j < 4; ++j) {
      int rloc = wm * 64 + m * 16 + g * 4 + j;
      int row = row_base + m * 16 + g * 4 + j;
      float bm = funmap(blockmin[rloc]);              // broadcast read
      float gmv = gm[m][j];
      float thr = fminf(gmv, bm) + MARGIN;
      float s0 = __fsub_rn(e2v[0], __fmul_rn(2.0f, acc[m][0][j]));
      float s1 = __fsub_rn(e2v[1], __fmul_rn(2.0f, acc[m][1][j]));
      float s2 = __fsub_rn(e2v[2], __fmul_rn(2.0f, acc[m][2][j]));
      float s3 = __fsub_rn(e2v[3], __fmul_rn(2.0f, acc[m][3][j]));
      if (s0 <= thr) { unsigned sl = atomicAdd(&cnt[row], 1u); if (sl < CAP) cand[(size_t)row * CAP + sl] = (ushort)(col_base + 0 * 16 + cl); }
      if (s1 <= thr) { unsigned sl = atomicAdd(&cnt[row], 1u); if (sl < CAP) cand[(size_t)row * CAP + sl] = (ushort)(col_base + 1 * 16 + cl); }
      if (s2 <= thr) { unsigned sl = atomicAdd(&cnt[row], 1u); if (sl < CAP) cand[(size_t)row * CAP + sl] = (ushort)(col_base + 2 * 16 + cl); }
      if (s3 <= thr) { unsigned sl = atomicAdd(&cnt[row], 1u); if (sl < CAP) cand[(size_t)row * CAP + sl] = (ushort)(col_base + 3 * 16 + cl); }
      // publish block min fire-and-forget (one lane per row, only if improving)
      if (wn == 0 && cl == 0 && bm < gmv) atomicMin(&rowMinU[row], fmap(bm));
    }
  }
}

// Fused: exact fp32-chain rescore (lex (s,idx) min = first-min-wins) + overflow
// full-scan fallback + gather + per-row loss partial. r2 computed inline.
__global__ __launch_bounds__(256) void k_rescore_gather(const float* __restrict__ z,
                                                        const float* __restrict__ cb,
                                                        const float* __restrict__ e2f,
                                                        const unsigned* __restrict__ cnt,
                                                        const ushort* __restrict__ cand,
                                                        float* __restrict__ out_q,
                                                        float* __restrict__ out_idx,
                                                        float* __restrict__ lpart) {
  int t = threadIdx.x, w = t >> 6, lane = t & 63;
  int row = blockIdx.x * 4 + w;
  const float* xp = z + (size_t)row * DDIM;
  const float4* xp4 = reinterpret_cast<const float4*>(xp);
  float4 x4 = xp4[lane];
  double rd = (double)x4.x * x4.x + (double)x4.y * x4.y + (double)x4.z * x4.z + (double)x4.w * x4.w;
#pragma unroll
  for (int off = 1; off < 64; off <<= 1) rd += __shfl_xor(rd, off);
  float r2v = (float)rd;                  // same summation as r6's k_prep (validated)

  unsigned n = cnt[row];
  float s = INFINITY; int ci = 0x7fffffff;
  if (n <= CAP) {
#pragma unroll
    for (int base = 0; base < CAP; base += 64) {
      int k_i = base + lane;
      if (k_i < (int)n) {
        int c = cand[(size_t)row * CAP + k_i];
        const float4* ep4 = reinterpret_cast<const float4*>(cb + (size_t)c * DDIM);
        float acc = 0.f;
#pragma unroll 4
        for (int k4 = 0; k4 < 64; ++k4) {          // k ascending, exact chain order
          float4 e = ep4[k4], x = xp4[k4];
          acc = __fmaf_rn(x.x, e.x, acc);
          acc = __fmaf_rn(x.y, e.y, acc);
          acc = __fmaf_rn(x.z, e.z, acc);
          acc = __fmaf_rn(x.w, e.w, acc);
        }
        float scv = __fsub_rn(__fadd_rn(r2v, e2f[c]), __fmul_rn(2.0f, acc));
        if (scv < s || (scv == s && c < ci)) { s = scv; ci = c; }
      }
    }
  } else {
    for (int base = 0; base < KCW; base += 64) {   // exact full-scan fallback
      int c = base + lane;
      const float4* ep4 = reinterpret_cast<const float4*>(cb + (size_t)c * DDIM);
      float acc = 0.f;
#pragma unroll 4
      for (int k4 = 0; k4 < 64; ++k4) {
        float4 e = ep4[k4], x = xp4[k4];
        acc = __fmaf_rn(x.x, e.x, acc);
        acc = __fmaf_rn(x.y, e.y, acc);
        acc = __fmaf_rn(x.z, e.z, acc);
        acc = __fmaf_rn(x.w, e.w, acc);
      }
      float scv = __fsub_rn(__fadd_rn(r2v, e2f[c]), __fmul_rn(2.0f, acc));
      if (scv < s) { s = scv; ci = c; }            // c ascending: first-wins
    }
  }
#pragma unroll
  for (int off = 1; off < 64; off <<= 1) {         // butterfly: all lanes get min
    float os = __shfl_xor(s, off); int oi = __shfl_xor(ci, off);
    if (os < s || (os == s && oi < ci)) { s = os; ci = oi; }
  }
  if (lane == 0) out_idx[row] = (float)ci;

  float4 qv = *reinterpret_cast<const float4*>(cb + (size_t)ci * DDIM + lane * 4);
  float* o = out_q + (size_t)row * DDIM + lane * 4; // out+1 base: scalar stores
  o[0] = qv.x; o[1] = qv.y; o[2] = qv.z; o[3] = qv.w;
  float dx = qv.x - x4.x, dy = qv.y - x4.y, dz = qv.z - x4.z, dw = qv.w - x4.w;
  double d = (double)dx * dx + (double)dy * dy + (double)dz * dz + (double)dw * dw;
#pragma unroll
  for (int off = 1; off < 64; off <<= 1) d += __shfl_xor(d, off);
  if (lane == 0) lpart[row] = (float)d;
}

__global__ __launch_bounds__(256) void k_loss(const float* __restrict__ lpart,
                                              float* __restrict__ out0) {
  __shared__ double red[256];
  int t = threadIdx.x;
  double s = 0.0;
  for (int j = t; j < NROWS; j += 256) s += lpart[j];  // fixed order -> deterministic
  red[t] = s;
  __syncthreads();
  for (int off = 128; off > 0; off >>= 1) {
    if (t < off) red[t] += red[t + off];
    __syncthreads();
  }
  if (t == 0) out0[0] = (float)(1.25 * red[0] / (double)((size_t)NROWS * DDIM));
}

extern "C" void kernel_launch(void* const* d_in, const int* in_sizes, int n_in,
                              void* d_out, int out_size, void* d_ws, size_t ws_size,
                              hipStream_t stream) {
  const float* z  = (const float*)d_in[0];   // [16,512,256] flat
  const float* cb = (const float*)d_in[1];   // [8192,256]
  float* out = (float*)d_out;
  char* ws = (char*)d_ws;
  const size_t HALF = (size_t)NROWS * DDIM;  // 2,097,152

  // bf16 copies in the out_q region (out+4 floats: 16B-aligned). Last 3 floats
  // of cbb overlap out_idx[0..2]; out_idx is written by k_rescore_gather, which
  // runs after the last zb/cbb read (k_score1). Recomputed every call.
  ushort* zb  = (ushort*)(out + 4);
  ushort* cbb = zb + HALF;

  // ws: e2f 32K | cnt 32K | rowMinU 32K (lpart overlays it after k_score1) |
  //     cand ushort 8192*128*2 = 2MB ; total 2,195,456 B (< 2,211,840 proven in r2)
  size_t off = 0;
  float*    e2f     = (float*)(ws + off);    off += NROWS * 4;
  unsigned* cnt     = (unsigned*)(ws + off); off += NROWS * 4;
  unsigned* rowMinU = (unsigned*)(ws + off);
  float*    lpart   = (float*)(ws + off);    off += NROWS * 4;   // overlays rowMinU
  ushort*   cand    = (ushort*)(ws + off);   off += (size_t)NROWS * CAP * 2;

  float* out_q   = out + 1;
  float* out_idx = out + 1 + HALF;

  k_prep_cast     <<<(2 * NROWS) / 4, 256, 0, stream>>>(z, cb, zb, cbb, e2f, rowMinU, cnt);
  k_score1        <<<64 * 32,         512, 0, stream>>>(zb, cbb, e2f, rowMinU, cnt, cand);
  k_rescore_gather<<<NROWS / 4,       256, 0, stream>>>(z, cb, e2f, cnt, cand, out_q, out_idx, lpart);
  k_loss          <<<1,               256, 0, stream>>>(lpart, out);
}

// Round 20
// 214.861 us; speedup vs baseline: 2.4482x; 2.4482x over previous
//
#include <hip/hip_runtime.h>
#include <hip/hip_bf16.h>
#include <math.h>

// VQ quantizer: LDS-free register-sweep bf16-MFMA prefilter + fp32-chain-exact rescore.
//   Exact semantics (validated r2/r4/r6): dist = fl32(fl32(r2+e2) - 2*fma_chain(x.e)),
//   argmin first-min-wins.
// Swapped-operand MFMA: mfma(A=cb_frag, B=z_frag) puts z-row on lane&15 ->
//   per-row running min is in-lane fmin + 2 shfl (no LDS, no barriers).
// Capture rule (r11/r12-validated): s(c) <= runmin + M; runmin = per-row prefix min,
//   cross-wave shared via device atomicMin(rowMinU). Any shared value >= true min
//   -> superset of all c with s_mfma(c) <= gmin + 2delta (~3e-4 <= M=5e-4); stale
//   reads only loosen -> safe. CAP=128; exact full-scan fallback on overflow.
// Round 20 = r12 (best passing, 207.9us) with ONE change: k_rescore_gather's
//   candidate chain software-pipelined (8-chunk register double-buffer, eA/eB
//   pair-unrolled) — r12's rescore was ~69us of exposed L2 latency under a
//   4cy/FMA dependent chain. Chain FMA order (k ascending) unchanged -> bit-exact.
// Outputs (float32 flat): [loss | quantized(8192*256) | indices(8192 as float)]

#define NROWS 8192
#define DDIM  256
#define KCW   8192
#define CAP   128
#define MARGIN 5e-4f

typedef __attribute__((ext_vector_type(8))) short short8;
typedef __attribute__((ext_vector_type(4))) float f32x4;

struct AFrag { short8 v[8]; f32x4 e2; };

__device__ inline unsigned fmap(float f) {
  unsigned b = __float_as_uint(f);
  return (b & 0x80000000u) ? ~b : (b | 0x80000000u);
}
__device__ inline float funmap(unsigned u) {
  unsigned b = (u & 0x80000000u) ? (u & 0x7FFFFFFFu) : ~u;
  return __uint_as_float(b);
}

// Fused: bf16 cast + e2 (f64->f32, cb rows) + rowMinU/cnt init (z rows).
__global__ __launch_bounds__(256) void k_prep_cast(const float* __restrict__ z,
                                                   const float* __restrict__ cb,
                                                   ushort* __restrict__ zb,
                                                   ushort* __restrict__ cbb,
                                                   float* __restrict__ e2f,
                                                   unsigned* __restrict__ rowMinU,
                                                   unsigned* __restrict__ cnt) {
  int t = threadIdx.x, w = t >> 6, lane = t & 63;
  int wid = blockIdx.x * 4 + w;           // 0..16383
  bool isCb = wid >= NROWS;
  int row = isCb ? wid - NROWS : wid;
  const float* src = (isCb ? cb : z) + (size_t)row * DDIM + lane * 4;
  float4 v = *reinterpret_cast<const float4*>(src);
  ushort4 o;
  __hip_bfloat16 bx = __float2bfloat16(v.x); o.x = *(ushort*)&bx;
  __hip_bfloat16 by = __float2bfloat16(v.y); o.y = *(ushort*)&by;
  __hip_bfloat16 bz = __float2bfloat16(v.z); o.z = *(ushort*)&bz;
  __hip_bfloat16 bw = __float2bfloat16(v.w); o.w = *(ushort*)&bw;
  ushort* dst = (isCb ? cbb : zb) + (size_t)row * DDIM + lane * 4;
  *reinterpret_cast<ushort4*>(dst) = o;
  if (isCb) {
    double d = (double)v.x * v.x + (double)v.y * v.y + (double)v.z * v.z + (double)v.w * v.w;
#pragma unroll
    for (int off = 1; off < 64; off <<= 1) d += __shfl_xor(d, off);
    if (lane == 0) e2f[row] = (float)d;
  } else {
    if (lane == 0) { rowMinU[row] = ~0u; cnt[row] = 0; }
  }
}

// Wave: 64 z-rows (4 n-frags x 16 on lane&15), sweeps 512 cb-cols (32 tiles of 16).
// z resident in VGPRs; cb fragments register-double-buffered (A0/A1). No LDS/barriers.
__global__ __launch_bounds__(256, 2) void k_sweep(const ushort* __restrict__ zb,
                                                  const ushort* __restrict__ cbb,
                                                  const float* __restrict__ e2f,
                                                  unsigned* __restrict__ rowMinU,
                                                  unsigned* __restrict__ cnt,
                                                  ushort* __restrict__ cand) {
  int t = threadIdx.x, w = t >> 6, lane = t & 63;
  int wid = blockIdx.x * 4 + w;           // 0..2047
  int rg = wid >> 4, sg = wid & 15;
  int R0 = rg * 64, C0 = sg * 512;
  int cl = lane & 15, g = lane >> 4;

  short8 Z[4][8];
#pragma unroll
  for (int n = 0; n < 4; ++n)
#pragma unroll
    for (int kk = 0; kk < 8; ++kk)
      Z[n][kk] = *reinterpret_cast<const short8*>(
          &zb[(size_t)(R0 + n * 16 + cl) * DDIM + kk * 32 + g * 8]);

  int rowIdx[4];
#pragma unroll
  for (int n = 0; n < 4; ++n) rowIdx[n] = R0 + n * 16 + cl;

  float runm[4] = {INFINITY, INFINITY, INFINITY, INFINITY};

  auto LOADA = [&](AFrag& A, int tile) {
    int CT = C0 + tile * 16;
#pragma unroll
    for (int kk = 0; kk < 8; ++kk)
      A.v[kk] = *reinterpret_cast<const short8*>(
          &cbb[(size_t)(CT + cl) * DDIM + kk * 32 + g * 8]);
    A.e2 = *reinterpret_cast<const f32x4*>(&e2f[CT + g * 4]);
  };

  auto COMPUTE = [&](const AFrag& A, int tile) {
    int CT = C0 + tile * 16;
    f32x4 acc[4];
#pragma unroll
    for (int n = 0; n < 4; ++n) acc[n] = (f32x4){0.f, 0.f, 0.f, 0.f};
#pragma unroll
    for (int kk = 0; kk < 8; ++kk)
#pragma unroll
      for (int n = 0; n < 4; ++n)
        acc[n] = __builtin_amdgcn_mfma_f32_16x16x32_bf16(A.v[kk], Z[n][kk], acc[n], 0, 0, 0);

    // D layout: M-idx (cb-col offset) = g*4+j, N-idx (z-row) = cl
#pragma unroll
    for (int n = 0; n < 4; ++n) {
      float s0 = __fsub_rn(A.e2[0], __fmul_rn(2.0f, acc[n][0]));
      float s1 = __fsub_rn(A.e2[1], __fmul_rn(2.0f, acc[n][1]));
      float s2 = __fsub_rn(A.e2[2], __fmul_rn(2.0f, acc[n][2]));
      float s3 = __fsub_rn(A.e2[3], __fmul_rn(2.0f, acc[n][3]));
      float jm = fminf(fminf(s0, s1), fminf(s2, s3));
      jm = fminf(jm, __shfl_xor(jm, 16));   // reduce over g (4 lanes, same cl)
      jm = fminf(jm, __shfl_xor(jm, 32));
      runm[n] = fminf(runm[n], jm);
      float thr = runm[n] + MARGIN;
      int row = rowIdx[n];
      int colb = CT + g * 4;
      if (s0 <= thr) { unsigned sl = atomicAdd(&cnt[row], 1u); if (sl < CAP) cand[(size_t)row * CAP + sl] = (ushort)(colb + 0); }
      if (s1 <= thr) { unsigned sl = atomicAdd(&cnt[row], 1u); if (sl < CAP) cand[(size_t)row * CAP + sl] = (ushort)(colb + 1); }
      if (s2 <= thr) { unsigned sl = atomicAdd(&cnt[row], 1u); if (sl < CAP) cand[(size_t)row * CAP + sl] = (ushort)(colb + 2); }
      if (s3 <= thr) { unsigned sl = atomicAdd(&cnt[row], 1u); if (sl < CAP) cand[(size_t)row * CAP + sl] = (ushort)(colb + 3); }
    }

    // cross-wave threshold sharing (early-heavy cadence: tiles 0,1,7,15,23,31)
    if (tile < 2 || (tile & 7) == 7) {
#pragma unroll
      for (int n = 0; n < 4; ++n) {
        if (g == n) atomicMin(&rowMinU[rowIdx[n]], fmap(runm[n]));
      }
#pragma unroll
      for (int n = 0; n < 4; ++n)
        runm[n] = fminf(runm[n], funmap(rowMinU[rowIdx[n]]));   // stale -> looser -> safe
    }
  };

  AFrag A0, A1;
  LOADA(A0, 0);
  for (int tile = 0; tile < 32; tile += 2) {     // pair-unrolled: no reg moves
    if (tile + 1 < 32) LOADA(A1, tile + 1);      // in flight during COMPUTE(A0)
    COMPUTE(A0, tile);
    if (tile + 2 < 32) LOADA(A0, tile + 2);      // in flight during COMPUTE(A1)
    COMPUTE(A1, tile + 1);
  }
}

// Fused: exact fp32-chain rescore (lex (s,idx) min = first-min-wins) + overflow
// full-scan fallback + gather + per-row loss partial. r2 computed inline.
// Round 20: candidate chain software-pipelined — 8 chunks of 32 k-elements in
// registers (eA/eB double buffer, pair-unrolled, static indices), next chunk's
// 8 independent dwordx4 loads issued before chaining the current chunk.
// FMA order unchanged (k ascending, x/y/z/w) -> bit-exact vs r12.
__global__ __launch_bounds__(256) void k_rescore_gather(const float* __restrict__ z,
                                                        const float* __restrict__ cb,
                                                        const float* __restrict__ e2f,
                                                        const unsigned* __restrict__ cnt,
                                                        const ushort* __restrict__ cand,
                                                        float* __restrict__ out_q,
                                                        float* __restrict__ out_idx,
                                                        float* __restrict__ lpart) {
  int t = threadIdx.x, w = t >> 6, lane = t & 63;
  int row = blockIdx.x * 4 + w;
  const float* xp = z + (size_t)row * DDIM;
  const float4* xp4 = reinterpret_cast<const float4*>(xp);
  float4 x4 = xp4[lane];
  double rd = (double)x4.x * x4.x + (double)x4.y * x4.y + (double)x4.z * x4.z + (double)x4.w * x4.w;
#pragma unroll
  for (int off = 1; off < 64; off <<= 1) rd += __shfl_xor(rd, off);
  float r2v = (float)rd;                  // same summation as r6's k_prep (validated)

  unsigned n = cnt[row];
  float s = INFINITY; int ci = 0x7fffffff;
  if (n <= CAP) {
#pragma unroll
    for (int base = 0; base < CAP; base += 64) {
      int k_i = base + lane;
      if (k_i < (int)n) {
        int c = cand[(size_t)row * CAP + k_i];
        const float4* ep4 = reinterpret_cast<const float4*>(cb + (size_t)c * DDIM);
        float4 eA[8], eB[8];
#pragma unroll
        for (int q = 0; q < 8; ++q) eA[q] = ep4[q];          // chunk 0 in flight
        float acc = 0.f;
#pragma unroll
        for (int ch = 0; ch < 8; ch += 2) {                  // chunks ascending
#pragma unroll
          for (int q = 0; q < 8; ++q) eB[q] = ep4[(ch + 1) * 8 + q];  // prefetch ch+1
#pragma unroll
          for (int q = 0; q < 8; ++q) {                      // chain chunk ch (regs)
            float4 e = eA[q], x = xp4[ch * 8 + q];
            acc = __fmaf_rn(x.x, e.x, acc);
            acc = __fmaf_rn(x.y, e.y, acc);
            acc = __fmaf_rn(x.z, e.z, acc);
            acc = __fmaf_rn(x.w, e.w, acc);
          }
          if (ch + 2 < 8) {
#pragma unroll
            for (int q = 0; q < 8; ++q) eA[q] = ep4[(ch + 2) * 8 + q]; // prefetch ch+2
          }
#pragma unroll
          for (int q = 0; q < 8; ++q) {                      // chain chunk ch+1 (regs)
            float4 e = eB[q], x = xp4[(ch + 1) * 8 + q];
            acc = __fmaf_rn(x.x, e.x, acc);
            acc = __fmaf_rn(x.y, e.y, acc);
            acc = __fmaf_rn(x.z, e.z, acc);
            acc = __fmaf_rn(x.w, e.w, acc);
          }
        }
        float scv = __fsub_rn(__fadd_rn(r2v, e2f[c]), __fmul_rn(2.0f, acc));
        if (scv < s || (scv == s && c < ci)) { s = scv; ci = c; }
      }
    }
  } else {
    for (int base = 0; base < KCW; base += 64) {   // exact full-scan fallback
      int c = base + lane;
      const float4* ep4 = reinterpret_cast<const float4*>(cb + (size_t)c * DDIM);
      float acc = 0.f;
#pragma unroll 4
      for (int k4 = 0; k4 < 64; ++k4) {
        float4 e = ep4[k4], x = xp4[k4];
        acc = __fmaf_rn(x.x, e.x, acc);
        acc = __fmaf_rn(x.y, e.y, acc);
        acc = __fmaf_rn(x.z, e.z, acc);
        acc = __fmaf_rn(x.w, e.w, acc);
      }
      float scv = __fsub_rn(__fadd_rn(r2v, e2f[c]), __fmul_rn(2.0f, acc));
      if (scv < s) { s = scv; ci = c; }            // c ascending: first-wins
    }
  }
#pragma unroll
  for (int off = 1; off < 64; off <<= 1) {         // butterfly: all lanes get min
    float os = __shfl_xor(s, off); int oi = __shfl_xor(ci, off);
    if (os < s || (os == s && oi < ci)) { s = os; ci = oi; }
  }
  if (lane == 0) out_idx[row] = (float)ci;

  float4 qv = *reinterpret_cast<const float4*>(cb + (size_t)ci * DDIM + lane * 4);
  float* o = out_q + (size_t)row * DDIM + lane * 4; // out+1 base: scalar stores
  o[0] = qv.x; o[1] = qv.y; o[2] = qv.z; o[3] = qv.w;
  float dx = qv.x - x4.x, dy = qv.y - x4.y, dz = qv.z - x4.z, dw = qv.w - x4.w;
  double d = (double)dx * dx + (double)dy * dy + (double)dz * dz + (double)dw * dw;
#pragma unroll
  for (int off = 1; off < 64; off <<= 1) d += __shfl_xor(d, off);
  if (lane == 0) lpart[row] = (float)d;
}

__global__ __launch_bounds__(256) void k_loss(const float* __restrict__ lpart,
                                              float* __restrict__ out0) {
  __shared__ double red[256];
  int t = threadIdx.x;
  double s = 0.0;
  for (int j = t; j < NROWS; j += 256) s += lpart[j];  // fixed order -> deterministic
  red[t] = s;
  __syncthreads();
  for (int off = 128; off > 0; off >>= 1) {
    if (t < off) red[t] += red[t + off];
    __syncthreads();
  }
  if (t == 0) out0[0] = (float)(1.25 * red[0] / (double)((size_t)NROWS * DDIM));
}

extern "C" void kernel_launch(void* const* d_in, const int* in_sizes, int n_in,
                              void* d_out, int out_size, void* d_ws, size_t ws_size,
                              hipStream_t stream) {
  const float* z  = (const float*)d_in[0];   // [16,512,256] flat
  const float* cb = (const float*)d_in[1];   // [8192,256]
  float* out = (float*)d_out;
  char* ws = (char*)d_ws;
  const size_t HALF = (size_t)NROWS * DDIM;  // 2,097,152

  // bf16 copies in the out_q region (out+4 floats: 16B-aligned). Last 3 floats
  // of cbb overlap out_idx[0..2]; out_idx is written by k_rescore_gather, which
  // runs after the last zb/cbb read (k_sweep). Recomputed every call.
  ushort* zb  = (ushort*)(out + 4);
  ushort* cbb = zb + HALF;

  // ws: e2f 32K | cnt 32K | rowMinU 32K (lpart overlays it after k_sweep) |
  //     cand ushort 8192*128*2 = 2MB ; total 2,195,456 B (< 2,211,840 proven in r2)
  size_t off = 0;
  float*    e2f     = (float*)(ws + off);    off += NROWS * 4;
  unsigned* cnt     = (unsigned*)(ws + off); off += NROWS * 4;
  unsigned* rowMinU = (unsigned*)(ws + off);
  float*    lpart   = (float*)(ws + off);    off += NROWS * 4;   // overlays rowMinU
  ushort*   cand    = (ushort*)(ws + off);   off += (size_t)NROWS * CAP * 2;

  float* out_q   = out + 1;
  float* out_idx = out + 1 + HALF;

  k_prep_cast     <<<(2 * NROWS) / 4, 256, 0, stream>>>(z, cb, zb, cbb, e2f, rowMinU, cnt);
  k_sweep         <<<512,             256, 0, stream>>>(zb, cbb, e2f, rowMinU, cnt, cand);
  k_rescore_gather<<<NROWS / 4,       256, 0, stream>>>(z, cb, e2f, cnt, cand, out_q, out_idx, lpart);
  k_loss          <<<1,               256, 0, stream>>>(lpart, out);
}